// Round 7
// baseline (320.843 us; speedup 1.0000x reference)
//
#include <hip/hip_runtime.h>
#include <math.h>

#define N 6144
#define MAXD 128      // list capacity; deg clamped to 127
#define NWORDS 96     // u64 words per row bitmap
#define NW32 192      // u32 words per row bitmap

typedef unsigned long long u64;
typedef unsigned int u32;
typedef unsigned char u8;
typedef float f4 __attribute__((ext_vector_type(4)));

// Bitmap bit order (permuted for float4 ballots in k_build):
//   u64 word W = c*4+p (c = 256-col chunk, p = float4 component), bit l
//   <-> column j = c*256 + 4l + p.  Virtual column index v = W*64 + l.

// LDS byte address of column j's count in the byte-packed adj2p layout
__device__ __forceinline__ int a_addr(int j) {
    int vdx = (j & ~255) | ((j & 3) << 6) | ((j >> 2) & 63);
    return (((vdx >> 2) & 7) << 10) | ((vdx >> 5) << 2) | (vdx & 3);
}

// full adder: (s, c) = a + b + ci
#define FA(s, c, a, b, ci) { u32 _t = (a) ^ (b); (s) = _t ^ (ci); (c) = ((a) & (b)) | ((ci) & _t); }

template <int START>
__device__ __forceinline__ void badd_from(u32* p, u32 cy) {
    #pragma unroll
    for (int q = START; q < 6; ++q) { u32 x = p[q] & cy; p[q] ^= cy; cy = x; }
    p[6] ^= cy;
}

// add 15 one-bit words into 7-plane bit-sliced counter: 11 FA + 4 injections
__device__ __forceinline__ void csa15(u32* p, const u32* x) {
    u32 s0,c0,s1,c1,s2,c2,s3,c3,s4,c4;
    FA(s0,c0, x[0], x[1], x[2]);
    FA(s1,c1, x[3], x[4], x[5]);
    FA(s2,c2, x[6], x[7], x[8]);
    FA(s3,c3, x[9], x[10], x[11]);
    FA(s4,c4, x[12], x[13], x[14]);
    u32 t0,d0,u0,d1;
    FA(t0,d0, s0, s1, s2);
    FA(u0,d1, s3, s4, t0);          // weight-1
    u32 e0,f0,e1,f1,e2,f2;
    FA(e0,f0, c0, c1, c2);
    FA(e1,f1, c3, c4, d0);
    FA(e2,f2, e0, e1, d1);          // weight-2
    u32 g0,h0;
    FA(g0,h0, f0, f1, f2);          // weight-4 / weight-8
    badd_from<0>(p, u0);
    badd_from<1>(p, e2);
    badd_from<2>(p, g0);
    badd_from<3>(p, h0);
}

// ---------------------------------------------------------------------------
// Kernel B: row bitsets + CSR row lists — ZERO global atomics.
// ---------------------------------------------------------------------------
__global__ __launch_bounds__(256) void k_build(
    const float* __restrict__ adj,
    u64* __restrict__ rowbits, int* __restrict__ row_cnt, int* __restrict__ row_list)
{
    int i = blockIdx.x;
    int t = threadIdx.x, w = t >> 6, lane = t & 63;
    __shared__ int wtot[4];

    const f4* ar = (const f4*)(adj + (long)i * N) + (w * 6) * 64;

    f4 v[6];
    #pragma unroll
    for (int c = 0; c < 6; ++c)
        v[c] = __builtin_nontemporal_load(ar + c * 64 + lane);

    u64 m[6][4];
    #pragma unroll
    for (int c = 0; c < 6; ++c) {
        m[c][0] = __ballot(v[c].x != 0.0f);
        m[c][1] = __ballot(v[c].y != 0.0f);
        m[c][2] = __ballot(v[c].z != 0.0f);
        m[c][3] = __ballot(v[c].w != 0.0f);
    }

    int tot = 0;
    #pragma unroll
    for (int c = 0; c < 6; ++c) {
        #pragma unroll
        for (int p = 0; p < 4; ++p) tot += __popcll(m[c][p]);
    }
    if (lane == 0) wtot[w] = tot;
    __syncthreads();
    int base = 0;
    #pragma unroll
    for (int q = 0; q < 4; ++q) if (q < w) base += wtot[q];

    u64* rb = rowbits + (long)i * NWORDS + w * 24;   // word (w*6+c)*4+p
    #pragma unroll
    for (int c = 0; c < 6; ++c) {
        #pragma unroll
        for (int p = 0; p < 4; ++p) {
            u64 mm = m[c][p];
            if (lane == 0) rb[c * 4 + p] = mm;
            if ((mm >> lane) & 1ull) {
                int rank = __popcll(mm & ((1ull << lane) - 1ull));
                int s = base + rank;
                int j = (w * 6 + c) * 256 + (lane << 2) + p;   // inverse bit map
                if (s < MAXD) row_list[(long)i * MAXD + s] = j;
            }
            base += __popcll(mm);
        }
    }
    if (t == 0) {
        int tt = wtot[0] + wtot[1] + wtot[2] + wtot[3];
        row_cnt[i] = tt < 127 ? tt : 127;
    }
}

// ---------------------------------------------------------------------------
// Fused kernel: blocks 0..191 = CSC build from CSR via parallel atomics
// (replaces trans+collist; each thread issues <=8 independent atomicAdds,
// no serialized bit loops — the R2 failure mode).  col_list stores
// a_addr(i) (LDS byte offset, consumer-ready).  Order nondeterministic but
// consumed only via integer sums -> output bit-identical.
// Blocks 192..959 = GEMM h = x@W + Wh1/Wh2.
// ---------------------------------------------------------------------------
__global__ __launch_bounds__(256) void k_csc_gemm(
    const int* __restrict__ row_cnt, const int* __restrict__ row_list,
    int* __restrict__ col_cnt, int* __restrict__ col_list,
    const float* __restrict__ x, const float* __restrict__ W,
    const float* __restrict__ a,
    float* __restrict__ h, float* __restrict__ Wh1, float* __restrict__ Wh2)
{
    __shared__ float Wl[128 * 64];   // 32 KB (one K-half of W)
    __shared__ float xt[8][256];     //  8 KB (8-row x tile)

    int t = threadIdx.x, w = t >> 6, lane = t & 63;
    int bid = blockIdx.x;

    if (bid < 192) {
        // ---- CSC path: 32 rows per block, 8 threads per row
        int i = bid * 32 + (t >> 3);
        int sub = t & 7;
        int deg = row_cnt[i];
        int ai = a_addr(i);
        const int* rl = row_list + (long)i * MAXD;
        for (int e = sub; e < deg; e += 8) {
            int j = rl[e];                       // coalesced 32B chunks
            int slot = atomicAdd(&col_cnt[j], 1);
            if (slot < MAXD) col_list[(long)j * MAXD + slot] = ai;
        }
        return;
    }

    // ---- GEMM path
    long i0 = (long)(bid - 192) * 8;

    // stage x tile: 8 rows x 256 f = 512 float4, coalesced
    {
        const float4* xs = (const float4*)(x + i0 * 256);
        float4* xd = (float4*)&xt[0][0];
        xd[t]       = xs[t];
        xd[256 + t] = xs[256 + t];
    }

    float acc0 = 0.f, acc1 = 0.f;
    int r0 = w * 2;                  // each wave owns 2 rows

    #pragma unroll
    for (int half = 0; half < 2; ++half) {
        __syncthreads();             // covers xt staging (half 0) / Wl reuse (half 1)
        {
            const float4* Ws = (const float4*)(W + half * 128 * 64);
            float4* Wd = (float4*)Wl;
            #pragma unroll
            for (int q = 0; q < 8; ++q) Wd[q * 256 + t] = Ws[q * 256 + t];
        }
        __syncthreads();
        const float* xr0 = &xt[r0][half * 128];
        const float* xr1 = &xt[r0 + 1][half * 128];
        #pragma unroll 8
        for (int kk = 0; kk < 128; ++kk) {
            float wv = Wl[kk * 64 + lane];   // stride-1 across lanes: conflict-free
            acc0 = fmaf(xr0[kk], wv, acc0);  // broadcast reads
            acc1 = fmaf(xr1[kk], wv, acc1);
        }
    }

    // epilogue: h rows + Wh1/Wh2 dot products (64-lane shuffle reduce)
    h[(i0 + r0)     * 64 + lane] = acc0;
    h[(i0 + r0 + 1) * 64 + lane] = acc1;
    float a1 = a[lane], a2 = a[64 + lane];
    float s10 = acc0 * a1, s20 = acc0 * a2;
    float s11 = acc1 * a1, s21 = acc1 * a2;
    #pragma unroll
    for (int off = 32; off; off >>= 1) {
        s10 += __shfl_xor(s10, off, 64);
        s20 += __shfl_xor(s20, off, 64);
        s11 += __shfl_xor(s11, off, 64);
        s21 += __shfl_xor(s21, off, 64);
    }
    if (lane == 0) {
        Wh1[i0 + r0]     = s10;  Wh2[i0 + r0]     = s20;
        Wh1[i0 + r0 + 1] = s11;  Wh2[i0 + r0 + 1] = s21;
    }
}

// ---------------------------------------------------------------------------
// Kernel C (256 threads): CSA on threads 0-191 (192 words); edge-score with
// 32 8-lane groups, 4-wide multi-accumulator gather (latency-chain break);
// aggregation/deg-0 over 4 waves.  (Verified R4 version.)
// ---------------------------------------------------------------------------
__global__ __launch_bounds__(256) void k_attn(
    const float* __restrict__ h, const float* __restrict__ Wh1, const float* __restrict__ Wh2,
    const u64* __restrict__ rowbits,
    const int* __restrict__ row_cnt, const int* __restrict__ row_list,
    const int* __restrict__ col_cnt, const int* __restrict__ col_list,
    const float* __restrict__ W_si, const float* __restrict__ W_ei,
    float* __restrict__ out)
{
    __shared__ u32 adj2p[8 * 256];   // byte-packed counts via a_addr(); 8 KB
    __shared__ int nbr[MAXD];
    __shared__ int ccbuf[MAXD];
    __shared__ float lrbuf[MAXD];
    __shared__ float ebuf[MAXD];
    __shared__ float part[256];
    __shared__ float sh_max, sh_sum;

    int i = blockIdx.x;
    int t = threadIdx.x, w = t >> 6, lane = t & 63;
    int deg = row_cnt[i];
    deg = deg < 127 ? deg : 127;

    if (deg == 0) {
        float acc = 0.f;
        for (int r = w; r < N; r += 4) acc += h[(long)r * 64 + lane];
        part[t] = acc;
        __syncthreads();
        if (w == 0) {
            float s = part[lane] + part[64 + lane] + part[128 + lane] + part[192 + lane];
            s *= (1.0f / N);
            out[(long)i * 64 + lane] = s > 0.f ? s : expm1f(s);
        }
        return;
    }

    float aWei = fabsf(W_ei[0]);
    float aWsi = fabsf(W_si[0]);

    // prologue: neighbor list + per-edge scalars (expansion barrier covers these)
    if (t < deg) {
        int j = row_list[(long)i * MAXD + t];
        nbr[t] = j;
        int cc = col_cnt[j];
        ccbuf[t] = cc < MAXD ? cc : MAXD;
        float z = Wh1[i] + Wh2[j];
        lrbuf[t] = aWei * (z > 0.f ? z : 0.2f * z);
    }

    // ---- adj2 accumulation: threads 0-191 own u32 words (bit-order-agnostic)
    if (t < NW32) {
        const u32* rb32 = (const u32*)rowbits;
        const int* rl = row_list + (long)i * MAXD;   // uniform base -> s_load
        u32 p[7] = {0,0,0,0,0,0,0};

        int m = 0;
        for (; m + 15 <= deg; m += 15) {
            u32 x[15];
            #pragma unroll
            for (int q = 0; q < 15; ++q) {
                int j = rl[m + q];                   // wave-uniform -> scalar load
                x[q] = rb32[(long)j * NW32 + t];
            }
            csa15(p, x);
        }
        if (m < deg) {
            u32 x[15];
            #pragma unroll
            for (int q = 0; q < 15; ++q) {
                int mq = m + q;
                int j = rl[mq < deg ? mq : 0];       // safe uniform index
                u32 vv = rb32[(long)j * NW32 + t];
                x[q] = (mq < deg) ? vv : 0u;
            }
            csa15(p, x);
        }

        // SWAR expansion: 4 bit-positions/nibble -> 4 bytes
        #pragma unroll
        for (int g = 0; g < 8; ++g) {
            u32 acc = 0;
            #pragma unroll
            for (int pl = 0; pl < 7; ++pl) {
                u32 nib = (p[pl] >> (4 * g)) & 0xFu;
                acc += (nib * (0x00204081u << pl)) & (0x01010101u << pl);
            }
            adj2p[g * 256 + t] = acc;                // lane-consecutive, conflict-free
        }
    }
    __syncthreads();

    const u8* adj2b = (const u8*)adj2p;

    // ---- edge scores: 8-lane group per edge; col_list holds pre-computed
    // a_addr offsets; 4 independent load->gather->add chains expose ILP.
    {
        int g = t >> 3, sub = t & 7;
        for (int e = g; e < deg; e += 32) {
            int cc = ccbuf[e];
            const int* cl = col_list + (long)nbr[e] * MAXD;
            u32 a30 = 0, a31 = 0, a32 = 0, a33 = 0;
            int q = sub;
            for (; q + 24 < cc; q += 32) {
                int k0 = cl[q];
                int k1 = cl[q + 8];
                int k2 = cl[q + 16];
                int k3 = cl[q + 24];
                a30 += (u32)adj2b[k0];
                a31 += (u32)adj2b[k1];
                a32 += (u32)adj2b[k2];
                a33 += (u32)adj2b[k3];
            }
            if (q + 8 < cc) {
                int k0 = cl[q];
                int k1 = cl[q + 8];
                a30 += (u32)adj2b[k0];
                a31 += (u32)adj2b[k1];
                q += 16;
            }
            if (q < cc) a32 += (u32)adj2b[cl[q]];
            u32 a3 = (a30 + a31) + (a32 + a33);
            a3 += __shfl_xor(a3, 1, 64);
            a3 += __shfl_xor(a3, 2, 64);
            a3 += __shfl_xor(a3, 4, 64);
            if (sub == 0) {
                u32 a2 = (u32)adj2b[a_addr(nbr[e])];
                ebuf[e] = lrbuf[e] + aWsi * (float)(1u + a2 + a3);
            }
        }
    }
    __syncthreads();

    // ---- softmax over deg neighbors (wave 0)
    if (w == 0) {
        float v = -3.4e38f;
        for (int idx = lane; idx < deg; idx += 64) v = fmaxf(v, ebuf[idx]);
        #pragma unroll
        for (int off = 32; off; off >>= 1) v = fmaxf(v, __shfl_xor(v, off, 64));
        if (lane == 0) sh_max = v;
    }
    __syncthreads();
    if (t < deg) ebuf[t] = expf(ebuf[t] - sh_max);
    __syncthreads();
    if (w == 0) {
        float s = 0.f;
        for (int idx = lane; idx < deg; idx += 64) s += ebuf[idx];
        #pragma unroll
        for (int off = 32; off; off >>= 1) s += __shfl_xor(s, off, 64);
        if (lane == 0) sh_sum = s;
    }
    __syncthreads();

    // ---- h_prime: 4 waves, two independent accumulator chains each
    float acc0 = 0.f, acc1 = 0.f;
    int e = w;
    for (; e + 4 < deg; e += 8) {
        acc0 = fmaf(ebuf[e],     h[(long)nbr[e]     * 64 + lane], acc0);
        acc1 = fmaf(ebuf[e + 4], h[(long)nbr[e + 4] * 64 + lane], acc1);
    }
    if (e < deg)
        acc0 = fmaf(ebuf[e], h[(long)nbr[e] * 64 + lane], acc0);
    part[t] = acc0 + acc1;
    __syncthreads();
    if (w == 0) {
        float s = part[lane] + part[64 + lane] + part[128 + lane] + part[192 + lane];
        s /= sh_sum;
        out[(long)i * 64 + lane] = s > 0.f ? s : expm1f(s);
    }
}

// ---------------------------------------------------------------------------
extern "C" void kernel_launch(void* const* d_in, const int* in_sizes, int n_in,
                              void* d_out, int out_size, void* d_ws, size_t ws_size,
                              hipStream_t stream) {
    const float* x    = (const float*)d_in[0];
    const float* adj  = (const float*)d_in[1];
    const float* W    = (const float*)d_in[2];
    const float* a    = (const float*)d_in[3];
    const float* W_si = (const float*)d_in[4];
    const float* W_ei = (const float*)d_in[5];
    float* out = (float*)d_out;

    char* ws = (char*)d_ws;
    size_t off = 0;
    auto alloc = [&](size_t bytes) -> void* {
        void* p = ws + off;
        off += (bytes + 255) & ~(size_t)255;
        return p;
    };
    u64*   rowbits  = (u64*)  alloc((size_t)N * NWORDS * sizeof(u64));   // 4.72 MB
    float* h        = (float*)alloc((size_t)N * 64 * sizeof(float));     // 1.57 MB
    float* Wh1      = (float*)alloc((size_t)N * sizeof(float));
    float* Wh2      = (float*)alloc((size_t)N * sizeof(float));
    int*   row_cnt  = (int*)  alloc((size_t)N * sizeof(int));
    int*   row_list = (int*)  alloc((size_t)N * MAXD * sizeof(int));     // 3.15 MB
    int*   col_cnt  = (int*)  alloc((size_t)N * sizeof(int));
    int*   col_list = (int*)  alloc((size_t)N * MAXD * sizeof(int));     // 3.15 MB

    // col_cnt must start at zero for the atomic slot allocation (24 KB)
    hipMemsetAsync(col_cnt, 0, (size_t)N * sizeof(int), stream);

    k_build   <<<N, 256, 0, stream>>>(adj, rowbits, row_cnt, row_list);
    k_csc_gemm<<<192 + 768, 256, 0, stream>>>(row_cnt, row_list, col_cnt, col_list,
                                              x, W, a, h, Wh1, Wh2);
    k_attn    <<<N, 256, 0, stream>>>(h, Wh1, Wh2, rowbits, row_cnt, row_list,
                                      col_cnt, col_list, W_si, W_ei, out);
}

// Round 9
// 289.549 us; speedup vs baseline: 1.1081x; 1.1081x over previous
//
#include <hip/hip_runtime.h>
#include <math.h>

#define N 6144
#define MAXD 128      // list capacity; deg clamped to 127
#define NWORDS 96     // u64 words per row bitmap
#define NW32 192      // u32 words per row bitmap

typedef unsigned long long u64;
typedef unsigned int u32;
typedef unsigned char u8;
typedef float f4 __attribute__((ext_vector_type(4)));

// Bitmap bit order (permuted for float4 ballots in k_build):
//   u64 word W = c*4+p (c = 256-col chunk, p = float4 component), bit l
//   <-> column j = c*256 + 4l + p.  Virtual column index v = W*64 + l.

// LDS byte address of column j's count in the byte-packed adj2p layout
__device__ __forceinline__ int a_addr(int j) {
    int vdx = (j & ~255) | ((j & 3) << 6) | ((j >> 2) & 63);
    return (((vdx >> 2) & 7) << 10) | ((vdx >> 5) << 2) | (vdx & 3);
}

// full adder: (s, c) = a + b + ci
#define FA(s, c, a, b, ci) { u32 _t = (a) ^ (b); (s) = _t ^ (ci); (c) = ((a) & (b)) | ((ci) & _t); }

template <int START>
__device__ __forceinline__ void badd_from(u32* p, u32 cy) {
    #pragma unroll
    for (int q = START; q < 6; ++q) { u32 x = p[q] & cy; p[q] ^= cy; cy = x; }
    p[6] ^= cy;
}

// add 15 one-bit words into 7-plane bit-sliced counter: 11 FA + 4 injections
__device__ __forceinline__ void csa15(u32* p, const u32* x) {
    u32 s0,c0,s1,c1,s2,c2,s3,c3,s4,c4;
    FA(s0,c0, x[0], x[1], x[2]);
    FA(s1,c1, x[3], x[4], x[5]);
    FA(s2,c2, x[6], x[7], x[8]);
    FA(s3,c3, x[9], x[10], x[11]);
    FA(s4,c4, x[12], x[13], x[14]);
    u32 t0,d0,u0,d1;
    FA(t0,d0, s0, s1, s2);
    FA(u0,d1, s3, s4, t0);          // weight-1
    u32 e0,f0,e1,f1,e2,f2;
    FA(e0,f0, c0, c1, c2);
    FA(e1,f1, c3, c4, d0);
    FA(e2,f2, e0, e1, d1);          // weight-2
    u32 g0,h0;
    FA(g0,h0, f0, f1, f2);          // weight-4 / weight-8
    badd_from<0>(p, u0);
    badd_from<1>(p, e2);
    badd_from<2>(p, g0);
    badd_from<3>(p, h0);
}

// 64x64 bit-matrix transpose across one wave (lane l holds row l as u64)
__device__ __forceinline__ u64 bit_transpose64(u64 x, int lane) {
    const u64 masks[6] = {0xAAAAAAAAAAAAAAAAull, 0xCCCCCCCCCCCCCCCCull,
                          0xF0F0F0F0F0F0F0F0ull, 0xFF00FF00FF00FF00ull,
                          0xFFFF0000FFFF0000ull, 0xFFFFFFFF00000000ull};
    #pragma unroll
    for (int k = 0; k < 6; ++k) {
        int s = 1 << k;
        u64 m = masks[k];
        u64 y = (u64)__shfl_xor((long long)x, s, 64);
        x = (lane & s) ? ((x & m) | ((y & m) >> s))
                       : ((x & ~m) | ((y & ~m) << s));
    }
    return x;
}

// ---------------------------------------------------------------------------
// Fused kernel: blocks 0..767 = GEMM h = x@W + Wh1/Wh2 (runs in the HBM-bound
// shadow of the build blocks; W read-broadcast from L2, only 8 KB LDS so
// build occupancy is unchanged).  Blocks 768..6911 = row bitsets + CSR lists.
// ---------------------------------------------------------------------------
#define GEMM_BLKS 768
__global__ __launch_bounds__(256) void k_build_gemm(
    const float* __restrict__ adj,
    u64* __restrict__ rowbits, int* __restrict__ row_cnt, int* __restrict__ row_list,
    const float* __restrict__ x, const float* __restrict__ W,
    const float* __restrict__ a,
    float* __restrict__ h, float* __restrict__ Wh1, float* __restrict__ Wh2)
{
    __shared__ union SMem {
        int wtot[4];         // build path
        float xt[8][256];    // gemm path (8 KB)
    } sm;

    int t = threadIdx.x, w = t >> 6, lane = t & 63;
    int bid = blockIdx.x;

    if (bid < GEMM_BLKS) {
        // ---- GEMM path: 8 rows/block, x-tile in LDS, W broadcast from L2
        long i0 = (long)bid * 8;
        {
            const float4* xs = (const float4*)(x + i0 * 256);
            float4* xd = (float4*)&sm.xt[0][0];
            xd[t]       = xs[t];
            xd[256 + t] = xs[256 + t];
        }
        __syncthreads();

        int r0 = w * 2;                  // each wave owns 2 rows
        const float* xr0 = &sm.xt[r0][0];
        const float* xr1 = &sm.xt[r0 + 1][0];
        float acc0 = 0.f, acc1 = 0.f;
        #pragma unroll 8
        for (int kk = 0; kk < 256; ++kk) {
            float wv = W[kk * 64 + lane];    // coalesced 256B/wave, L2-resident
            acc0 = fmaf(xr0[kk], wv, acc0);  // LDS broadcast reads
            acc1 = fmaf(xr1[kk], wv, acc1);
        }

        // epilogue: h rows + Wh1/Wh2 dot products (64-lane shuffle reduce)
        h[(i0 + r0)     * 64 + lane] = acc0;
        h[(i0 + r0 + 1) * 64 + lane] = acc1;
        float a1 = a[lane], a2 = a[64 + lane];
        float s10 = acc0 * a1, s20 = acc0 * a2;
        float s11 = acc1 * a1, s21 = acc1 * a2;
        #pragma unroll
        for (int off = 32; off; off >>= 1) {
            s10 += __shfl_xor(s10, off, 64);
            s20 += __shfl_xor(s20, off, 64);
            s11 += __shfl_xor(s11, off, 64);
            s21 += __shfl_xor(s21, off, 64);
        }
        if (lane == 0) {
            Wh1[i0 + r0]     = s10;  Wh2[i0 + r0]     = s20;
            Wh1[i0 + r0 + 1] = s11;  Wh2[i0 + r0 + 1] = s21;
        }
        return;
    }

    // ---- build path (verified R1 k_build, i = bid - GEMM_BLKS)
    int i = bid - GEMM_BLKS;

    const f4* ar = (const f4*)(adj + (long)i * N) + (w * 6) * 64;

    f4 v[6];
    #pragma unroll
    for (int c = 0; c < 6; ++c)
        v[c] = __builtin_nontemporal_load(ar + c * 64 + lane);

    u64 m[6][4];
    #pragma unroll
    for (int c = 0; c < 6; ++c) {
        m[c][0] = __ballot(v[c].x != 0.0f);
        m[c][1] = __ballot(v[c].y != 0.0f);
        m[c][2] = __ballot(v[c].z != 0.0f);
        m[c][3] = __ballot(v[c].w != 0.0f);
    }

    int tot = 0;
    #pragma unroll
    for (int c = 0; c < 6; ++c) {
        #pragma unroll
        for (int p = 0; p < 4; ++p) tot += __popcll(m[c][p]);
    }
    if (lane == 0) sm.wtot[w] = tot;
    __syncthreads();
    int base = 0;
    #pragma unroll
    for (int q = 0; q < 4; ++q) if (q < w) base += sm.wtot[q];

    u64* rb = rowbits + (long)i * NWORDS + w * 24;   // word (w*6+c)*4+p
    #pragma unroll
    for (int c = 0; c < 6; ++c) {
        #pragma unroll
        for (int p = 0; p < 4; ++p) {
            u64 mm = m[c][p];
            if (lane == 0) rb[c * 4 + p] = mm;
            if ((mm >> lane) & 1ull) {
                int rank = __popcll(mm & ((1ull << lane) - 1ull));
                int s = base + rank;
                int j = (w * 6 + c) * 256 + (lane << 2) + p;   // inverse bit map
                if (s < MAXD) row_list[(long)i * MAXD + s] = j;
            }
            base += __popcll(mm);
        }
    }
    if (t == 0) {
        int tt = sm.wtot[0] + sm.wtot[1] + sm.wtot[2] + sm.wtot[3];
        row_cnt[i] = tt < 127 ? tt : 127;
    }
}

// ---------------------------------------------------------------------------
// Kernel B2: bit-transpose rowbits -> colbits (64x64 tile per wave)
// ---------------------------------------------------------------------------
__global__ __launch_bounds__(256) void k_trans(
    const u64* __restrict__ rowbits, u64* __restrict__ colbits)
{
    int w = threadIdx.x >> 6, lane = threadIdx.x & 63;
    int tile = blockIdx.x * 4 + w;
    int tr = tile / 96, tc = tile - tr * 96;
    u64 x = rowbits[(long)(tr * 64 + lane) * NWORDS + tc];
    x = bit_transpose64(x, lane);
    colbits[(long)(tc * 64 + lane) * NWORDS + tr] = x;
}

// ---------------------------------------------------------------------------
// Kernel B3: CSC lists from colbits — no atomics, wave per virtual column.
// Stores a_addr(row) (LDS byte offset into adj2p) — consumer-ready.
// ---------------------------------------------------------------------------
__global__ __launch_bounds__(256) void k_collist(
    const u64* __restrict__ colbits,
    int* __restrict__ col_cnt, int* __restrict__ col_list)
{
    int w = threadIdx.x >> 6, lane = threadIdx.x & 63;
    int v = blockIdx.x * 4 + w;                       // virtual column
    int j = (v & ~255) | ((v & 63) << 2) | ((v >> 6) & 3);   // real column

    u64 w0 = 0, w1 = 0;
    if (lane < 48) {
        const u64* p2 = colbits + (long)v * NWORDS + lane * 2;
        w0 = p2[0]; w1 = p2[1];
    }
    int pc = __popcll(w0) + __popcll(w1);
    int incl = pc;
    #pragma unroll
    for (int off = 1; off < 64; off <<= 1) {
        int y = __shfl_up(incl, off, 64);
        if (lane >= off) incl += y;
    }
    int excl = incl - pc;
    int total = __shfl(incl, 63, 64);
    if (lane == 0) col_cnt[j] = total;

    int* cl = col_list + (long)j * MAXD;
    int s = excl;
    int ibase = lane * 128;
    while (w0) {
        int b = __ffsll((long long)w0) - 1; w0 &= w0 - 1;
        if (s < MAXD) cl[s] = a_addr(ibase + b);
        ++s;
    }
    ibase += 64;
    while (w1) {
        int b = __ffsll((long long)w1) - 1; w1 &= w1 - 1;
        if (s < MAXD) cl[s] = a_addr(ibase + b);
        ++s;
    }
}

// ---------------------------------------------------------------------------
// Kernel C (256 threads): CSA on threads 0-191 (192 words); edge-score with
// 32 8-lane groups, 4-wide multi-accumulator gather; aggregation over 4 waves.
// (Verified R4 version.)
// ---------------------------------------------------------------------------
__global__ __launch_bounds__(256) void k_attn(
    const float* __restrict__ h, const float* __restrict__ Wh1, const float* __restrict__ Wh2,
    const u64* __restrict__ rowbits,
    const int* __restrict__ row_cnt, const int* __restrict__ row_list,
    const int* __restrict__ col_cnt, const int* __restrict__ col_list,
    const float* __restrict__ W_si, const float* __restrict__ W_ei,
    float* __restrict__ out)
{
    __shared__ u32 adj2p[8 * 256];   // byte-packed counts via a_addr(); 8 KB
    __shared__ int nbr[MAXD];
    __shared__ int ccbuf[MAXD];
    __shared__ float lrbuf[MAXD];
    __shared__ float ebuf[MAXD];
    __shared__ float part[256];
    __shared__ float sh_max, sh_sum;

    int i = blockIdx.x;
    int t = threadIdx.x, w = t >> 6, lane = t & 63;
    int deg = row_cnt[i];
    deg = deg < 127 ? deg : 127;

    if (deg == 0) {
        float acc = 0.f;
        for (int r = w; r < N; r += 4) acc += h[(long)r * 64 + lane];
        part[t] = acc;
        __syncthreads();
        if (w == 0) {
            float s = part[lane] + part[64 + lane] + part[128 + lane] + part[192 + lane];
            s *= (1.0f / N);
            out[(long)i * 64 + lane] = s > 0.f ? s : expm1f(s);
        }
        return;
    }

    float aWei = fabsf(W_ei[0]);
    float aWsi = fabsf(W_si[0]);

    // prologue: neighbor list + per-edge scalars (expansion barrier covers these)
    if (t < deg) {
        int j = row_list[(long)i * MAXD + t];
        nbr[t] = j;
        int cc = col_cnt[j];
        ccbuf[t] = cc < MAXD ? cc : MAXD;
        float z = Wh1[i] + Wh2[j];
        lrbuf[t] = aWei * (z > 0.f ? z : 0.2f * z);
    }

    // ---- adj2 accumulation: threads 0-191 own u32 words (bit-order-agnostic)
    if (t < NW32) {
        const u32* rb32 = (const u32*)rowbits;
        const int* rl = row_list + (long)i * MAXD;   // uniform base -> s_load
        u32 p[7] = {0,0,0,0,0,0,0};

        int m = 0;
        for (; m + 15 <= deg; m += 15) {
            u32 x[15];
            #pragma unroll
            for (int q = 0; q < 15; ++q) {
                int j = rl[m + q];                   // wave-uniform -> scalar load
                x[q] = rb32[(long)j * NW32 + t];
            }
            csa15(p, x);
        }
        if (m < deg) {
            u32 x[15];
            #pragma unroll
            for (int q = 0; q < 15; ++q) {
                int mq = m + q;
                int j = rl[mq < deg ? mq : 0];       // safe uniform index
                u32 vv = rb32[(long)j * NW32 + t];
                x[q] = (mq < deg) ? vv : 0u;
            }
            csa15(p, x);
        }

        // SWAR expansion: 4 bit-positions/nibble -> 4 bytes
        #pragma unroll
        for (int g = 0; g < 8; ++g) {
            u32 acc = 0;
            #pragma unroll
            for (int pl = 0; pl < 7; ++pl) {
                u32 nib = (p[pl] >> (4 * g)) & 0xFu;
                acc += (nib * (0x00204081u << pl)) & (0x01010101u << pl);
            }
            adj2p[g * 256 + t] = acc;                // lane-consecutive, conflict-free
        }
    }
    __syncthreads();

    const u8* adj2b = (const u8*)adj2p;

    // ---- edge scores: 8-lane group per edge; col_list holds pre-computed
    // a_addr offsets; 4 independent load->gather->add chains expose ILP.
    {
        int g = t >> 3, sub = t & 7;
        for (int e = g; e < deg; e += 32) {
            int cc = ccbuf[e];
            const int* cl = col_list + (long)nbr[e] * MAXD;
            u32 a30 = 0, a31 = 0, a32 = 0, a33 = 0;
            int q = sub;
            for (; q + 24 < cc; q += 32) {
                int k0 = cl[q];
                int k1 = cl[q + 8];
                int k2 = cl[q + 16];
                int k3 = cl[q + 24];
                a30 += (u32)adj2b[k0];
                a31 += (u32)adj2b[k1];
                a32 += (u32)adj2b[k2];
                a33 += (u32)adj2b[k3];
            }
            if (q + 8 < cc) {
                int k0 = cl[q];
                int k1 = cl[q + 8];
                a30 += (u32)adj2b[k0];
                a31 += (u32)adj2b[k1];
                q += 16;
            }
            if (q < cc) a32 += (u32)adj2b[cl[q]];
            u32 a3 = (a30 + a31) + (a32 + a33);
            a3 += __shfl_xor(a3, 1, 64);
            a3 += __shfl_xor(a3, 2, 64);
            a3 += __shfl_xor(a3, 4, 64);
            if (sub == 0) {
                u32 a2 = (u32)adj2b[a_addr(nbr[e])];
                ebuf[e] = lrbuf[e] + aWsi * (float)(1u + a2 + a3);
            }
        }
    }
    __syncthreads();

    // ---- softmax over deg neighbors (wave 0)
    if (w == 0) {
        float v = -3.4e38f;
        for (int idx = lane; idx < deg; idx += 64) v = fmaxf(v, ebuf[idx]);
        #pragma unroll
        for (int off = 32; off; off >>= 1) v = fmaxf(v, __shfl_xor(v, off, 64));
        if (lane == 0) sh_max = v;
    }
    __syncthreads();
    if (t < deg) ebuf[t] = expf(ebuf[t] - sh_max);
    __syncthreads();
    if (w == 0) {
        float s = 0.f;
        for (int idx = lane; idx < deg; idx += 64) s += ebuf[idx];
        #pragma unroll
        for (int off = 32; off; off >>= 1) s += __shfl_xor(s, off, 64);
        if (lane == 0) sh_sum = s;
    }
    __syncthreads();

    // ---- h_prime: 4 waves, two independent accumulator chains each
    float acc0 = 0.f, acc1 = 0.f;
    int e = w;
    for (; e + 4 < deg; e += 8) {
        acc0 = fmaf(ebuf[e],     h[(long)nbr[e]     * 64 + lane], acc0);
        acc1 = fmaf(ebuf[e + 4], h[(long)nbr[e + 4] * 64 + lane], acc1);
    }
    if (e < deg)
        acc0 = fmaf(ebuf[e], h[(long)nbr[e] * 64 + lane], acc0);
    part[t] = acc0 + acc1;
    __syncthreads();
    if (w == 0) {
        float s = part[lane] + part[64 + lane] + part[128 + lane] + part[192 + lane];
        s /= sh_sum;
        out[(long)i * 64 + lane] = s > 0.f ? s : expm1f(s);
    }
}

// ---------------------------------------------------------------------------
extern "C" void kernel_launch(void* const* d_in, const int* in_sizes, int n_in,
                              void* d_out, int out_size, void* d_ws, size_t ws_size,
                              hipStream_t stream) {
    const float* x    = (const float*)d_in[0];
    const float* adj  = (const float*)d_in[1];
    const float* W    = (const float*)d_in[2];
    const float* a    = (const float*)d_in[3];
    const float* W_si = (const float*)d_in[4];
    const float* W_ei = (const float*)d_in[5];
    float* out = (float*)d_out;

    char* ws = (char*)d_ws;
    size_t off = 0;
    auto alloc = [&](size_t bytes) -> void* {
        void* p = ws + off;
        off += (bytes + 255) & ~(size_t)255;
        return p;
    };
    u64*   rowbits  = (u64*)  alloc((size_t)N * NWORDS * sizeof(u64));   // 4.72 MB
    u64*   colbits  = (u64*)  alloc((size_t)N * NWORDS * sizeof(u64));   // 4.72 MB
    float* h        = (float*)alloc((size_t)N * 64 * sizeof(float));     // 1.57 MB
    float* Wh1      = (float*)alloc((size_t)N * sizeof(float));
    float* Wh2      = (float*)alloc((size_t)N * sizeof(float));
    int*   row_cnt  = (int*)  alloc((size_t)N * sizeof(int));
    int*   row_list = (int*)  alloc((size_t)N * MAXD * sizeof(int));     // 3.15 MB
    int*   col_cnt  = (int*)  alloc((size_t)N * sizeof(int));
    int*   col_list = (int*)  alloc((size_t)N * MAXD * sizeof(int));     // 3.15 MB

    k_build_gemm<<<GEMM_BLKS + N, 256, 0, stream>>>(adj, rowbits, row_cnt, row_list,
                                                    x, W, a, h, Wh1, Wh2);
    k_trans  <<<(96 * 96) / 4, 256, 0, stream>>>(rowbits, colbits);
    k_collist<<<N / 4, 256, 0, stream>>>(colbits, col_cnt, col_list);
    k_attn   <<<N, 256, 0, stream>>>(h, Wh1, Wh2, rowbits, row_cnt, row_list,
                                     col_cnt, col_list, W_si, W_ei, out);
}